// Round 14
// baseline (1512.644 us; speedup 1.0000x reference)
//
#include <hip/hip_runtime.h>

#define NUu 100000
#define NIi 100000
#define NAa 10000
#define DD  64
#define NN0 (NUu + NIi)   // 200000
#define NN1 (NUu + NAa)   // 110000

typedef unsigned int uint;
typedef unsigned short ushort;

// ---------------- bf16 / val14 helpers ----------------

__device__ __forceinline__ uint pack_bf2(float x, float y) {
    uint a = __float_as_uint(x);
    uint b = __float_as_uint(y);
    a = (a + 0x7fffu + ((a >> 16) & 1u)) >> 16;          // RNE low half
    b = (b + 0x7fffu + ((b >> 16) & 1u)) & 0xffff0000u;  // RNE high half
    return (a & 0xffffu) | b;
}
__device__ __forceinline__ float bflo(uint w) { return __uint_as_float(w << 16); }
__device__ __forceinline__ float bfhi(uint w) { return __uint_as_float(w & 0xffff0000u); }

// positive val -> 14-bit float (e8m6): bf16 RNE then drop 1 mantissa bit (rounded)
__device__ __forceinline__ uint enc14(float v) {
    uint u = __float_as_uint(v);
    uint bf = (u + 0x7fffu + ((u >> 16) & 1u)) >> 16;
    return ((bf + 1u) >> 1) & 0x3FFFu;
}
__device__ __forceinline__ float dec14(uint e) { return __uint_as_float(e << 17); }

// convert all three embeddings fp32 -> bf16 SPLIT PLANES (lo = dims 0..31, hi = 32..63)
__global__ void k_f2bf3s(const float4* __restrict__ su, const float4* __restrict__ si,
                         const float4* __restrict__ sa,
                         uint2* __restrict__ ulo, uint2* __restrict__ uhi,
                         uint2* __restrict__ ilo, uint2* __restrict__ ihi,
                         uint2* __restrict__ alo, uint2* __restrict__ ahi) {
    int i = blockIdx.x * blockDim.x + threadIdx.x;
    const int nu = NUu * 16, ni = NIi * 16, na = NAa * 16;
    const float4* s;
    uint2 *dlo, *dhi;
    int j;
    if (i < nu) { s = su; dlo = ulo; dhi = uhi; j = i; }
    else if (i < nu + ni) { s = si; dlo = ilo; dhi = ihi; j = i - nu; }
    else if (i < nu + ni + na) { s = sa; dlo = alo; dhi = ahi; j = i - nu - ni; }
    else return;
    float4 v = s[j];
    uint2 o;
    o.x = pack_bf2(v.x, v.y);
    o.y = pack_bf2(v.z, v.w);
    int n = j >> 4, k = j & 15;
    uint2* d = (k < 8) ? dlo : dhi;
    d[n * 8 + (k & 7)] = o;
}

// ---------------- CSR build (arena bins, single partition pass) ----------------

#define P1_ITER 8
#define SEG_CAP 9472      // max edges per bin

// init all five graphs' bin cursors to b*cap (arena bases); slots of 1024
__global__ void k_arenainit(int* __restrict__ bc,
                            int nb0, int nb1, int nb2, int nb3, int nb4,
                            int c0, int c1, int c2, int c3, int c4) {
    int t = threadIdx.x;
    if (t < nb0) bc[t] = t * c0;
    if (t < nb1) bc[1024 + t] = t * c1;
    if (t < nb2) bc[2048 + t] = t * c2;
    if (t < nb3) bc[3072 + t] = t * c3;
    if (t < nb4) bc[4096 + t] = t * c4;
}

// P1: single pass — LDS bin histogram -> block reservation -> ONE 8B staged write/edge.
// stage = {(rowlow<<18)|col, fp32 val bits}
__global__ void __launch_bounds__(1024)
k_part1(const int* __restrict__ row, const int* __restrict__ col,
        const float* __restrict__ val, int* __restrict__ binCur,
        int2* __restrict__ stage, int E, int shift, int nbins, int cap) {
    __shared__ int h[1024];
    for (int t = threadIdx.x; t < nbins; t += blockDim.x) h[t] = 0;
    __syncthreads();
    int e0 = blockIdx.x * (blockDim.x * P1_ITER) + threadIdx.x;
    int r[P1_ITER];
#pragma unroll
    for (int i = 0; i < P1_ITER; ++i) {
        int e = e0 + i * blockDim.x;
        r[i] = (e < E) ? row[e] : -1;
        if (r[i] >= 0) atomicAdd(&h[r[i] >> shift], 1);
    }
    __syncthreads();
    for (int t = threadIdx.x; t < nbins; t += blockDim.x) {
        int c = h[t];
        h[t] = c ? atomicAdd(binCur + t, c) : 0;
    }
    __syncthreads();
#pragma unroll
    for (int i = 0; i < P1_ITER; ++i) {
        int e = e0 + i * blockDim.x;
        if (e < E) {
            int rr = r[i];
            int b = rr >> shift;
            int pos = atomicAdd(&h[b], 1);
            if (pos < (b + 1) * cap) {            // arena overflow guard (~11 sigma)
                int2 p;
                p.x = ((rr & ((1 << shift) - 1)) << 18) | col[e];
                p.y = __float_as_int(val[e]);
                stage[pos] = p;
            }
        }
    }
}

// P2: one block per bin. LDS-stage segment once, per-row count+scan -> rp2{start,end},
// then exact placement writing the 4B packed payload (col<<14)|enc14(val).
__global__ void __launch_bounds__(1024)
k_part2(const int* __restrict__ binCur, const int2* __restrict__ stage,
        uint* __restrict__ csr, int2* __restrict__ rp2, int N, int shift, int cap) {
    __shared__ int2 seg[SEG_CAP];
    __shared__ int h[512];
    __shared__ int s[512];
    int tid = threadIdx.x;
    int rbase = blockIdx.x << shift;
    int nr = min(1 << shift, N - rbase);
    int es = blockIdx.x * cap;
    int ee = min(binCur[blockIdx.x], es + cap);
    int n = ee - es;                              // n <= cap <= SEG_CAP
    if (tid < 512) h[tid] = 0;
    for (int i = tid; i < n; i += blockDim.x) seg[i] = stage[es + i];
    __syncthreads();
    for (int i = tid; i < n; i += blockDim.x)
        atomicAdd(&h[seg[i].x >> 18], 1);
    __syncthreads();
    int v = (tid < 512) ? h[tid] : 0;
    if (tid < 512) s[tid] = v;
    __syncthreads();
    for (int off = 1; off < 512; off <<= 1) {
        int t = (tid < 512 && tid >= off) ? s[tid - off] : 0;
        __syncthreads();
        if (tid < 512) s[tid] += t;
        __syncthreads();
    }
    if (tid < 512) h[tid] = es + s[tid] - v;      // row cursor
    if (tid < nr) {
        int st = es + s[tid] - v;
        rp2[rbase + tid] = make_int2(st, st + v);
    }
    __syncthreads();
    for (int i = tid; i < n; i += blockDim.x) {
        int2 p = seg[i];
        int pos = atomicAdd(&h[p.x >> 18], 1);
        csr[pos] = (((uint)(p.x & 0x3ffff)) << 14) | enc14(__int_as_float(p.y));
    }
}

// ------------- SpMM half-plane (32 dims; operand row = 16 uints = 64B) -------------
// lane = q*16 + d8 ; quarter q owns one edge slot; lane reads 1 uint = dims 2d8,2d8+1.
// MODE 0: plain — yp = pack(a)          (plane output, 16 uints/row)
// MODE 1: final — out = 0.25*(emb + y1 + y2 + a) for this plane's 32 dims;
//                 fp32 out split U/I at dOff, optional full-row bf16 outIb.
template <int MODE, bool SS>
__global__ void k_spmmh(const int2* __restrict__ rp2, const uint* __restrict__ csr,
                        const uint* __restrict__ xbA, const uint* __restrict__ xbB,
                        int split, int dOff,
                        const float* __restrict__ embA, const float* __restrict__ embB,
                        const uint* __restrict__ y1p, const uint* __restrict__ y2p,
                        float* __restrict__ outU, float* __restrict__ outI,
                        uint* __restrict__ outIb, uint* __restrict__ yp, int nrows) {
    int r = blockIdx.x * (blockDim.x >> 6) + (threadIdx.x >> 6);
    if (r >= nrows) return;
    int lane = threadIdx.x & 63;
    int q = lane >> 4;        // edge slot within group of 4
    int d8 = lane & 15;       // uint index within 16-uint plane row

    int2 se = rp2[r];
    int s0 = se.x, e0 = se.y;
    float a0 = 0.f, a1 = 0.f;
    int i = s0;
    for (; i + 32 <= e0; i += 32) {
        uint pe[8];
#pragma unroll
        for (int s = 0; s < 8; ++s)
            pe[s] = csr[i + 4 * s + q];
        uint wv[8];
#pragma unroll
        for (int s = 0; s < 8; ++s) {
            int c = (int)(pe[s] >> 14);
            const uint* b = SS ? ((c < split) ? xbA + (((long long)c) << 4)
                                             : xbB + (((long long)(c - split)) << 4))
                               : xbA + (((long long)c) << 4);
            wv[s] = b[d8];
        }
#pragma unroll
        for (int s = 0; s < 8; ++s) {
            float v = dec14(pe[s] & 0x3FFFu);
            a0 += v * bflo(wv[s]); a1 += v * bfhi(wv[s]);
        }
    }
    for (; i + 8 <= e0; i += 8) {
        uint p0 = csr[i + q];
        uint p1 = csr[i + 4 + q];
        int c0 = (int)(p0 >> 14), c1 = (int)(p1 >> 14);
        const uint* b0 = SS ? ((c0 < split) ? xbA + (((long long)c0) << 4)
                                            : xbB + (((long long)(c0 - split)) << 4))
                            : xbA + (((long long)c0) << 4);
        const uint* b1 = SS ? ((c1 < split) ? xbA + (((long long)c1) << 4)
                                            : xbB + (((long long)(c1 - split)) << 4))
                            : xbA + (((long long)c1) << 4);
        uint w0 = b0[d8], w1 = b1[d8];
        float v0 = dec14(p0 & 0x3FFFu);
        float v1 = dec14(p1 & 0x3FFFu);
        a0 += v0 * bflo(w0); a1 += v0 * bfhi(w0);
        a0 += v1 * bflo(w1); a1 += v1 * bfhi(w1);
    }
    for (; i < e0; i += 4) {
        int idx = i + q;
        uint pe = (idx < e0) ? csr[idx] : 0u;    // col 0, val 0 pad
        int c = (int)(pe >> 14);
        const uint* b = SS ? ((c < split) ? xbA + (((long long)c) << 4)
                                          : xbB + (((long long)(c - split)) << 4))
                           : xbA + (((long long)c) << 4);
        uint w = b[d8];
        float v = dec14(pe & 0x3FFFu);
        a0 += v * bflo(w); a1 += v * bfhi(w);
    }
    a0 += __shfl_xor(a0, 16); a0 += __shfl_xor(a0, 32);
    a1 += __shfl_xor(a1, 16); a1 += __shfl_xor(a1, 32);

    if (q != 0) return;
    if (MODE == 0) {
        yp[(((long long)r) << 4) + d8] = pack_bf2(a0, a1);
    } else {
        long long offf = (((long long)r) << 6) + dOff + 2 * d8;   // fp32 index
        float2 e2;
        if (r < split) e2 = *(const float2*)(embA + offf);
        else           e2 = *(const float2*)(embB + (offf - (((long long)split) << 6)));
        uint w1 = y1p[(((long long)r) << 4) + d8];
        uint w2 = y2p[(((long long)r) << 4) + d8];
        float s0f = 0.25f * (e2.x + bflo(w1) + bflo(w2) + a0);
        float s1f = 0.25f * (e2.y + bfhi(w1) + bfhi(w2) + a1);
        float2 o; o.x = s0f; o.y = s1f;
        if (r < split) {
            *(float2*)(outU + offf) = o;
        } else {
            *(float2*)(outI + (offf - (((long long)split) << 6))) = o;
            if (outIb)
                outIb[(((long long)(r - split)) << 5) + (dOff >> 1) + d8] = pack_bf2(s0f, s1f);
        }
    }
}

// ------------- SpMM full-row (64 dims; for normalize modes, g3/g4/g5) -------------
// MODE 2: yf = normalize(a) ; MODE 3: yf = 0.5*normalize(a) + 0.5*base
template <int MODE>
__global__ void k_spmm(const int2* __restrict__ rp2, const uint* __restrict__ csr,
                       const uint* __restrict__ xb,
                       float* __restrict__ yf, const float* __restrict__ base, int nrows) {
    int r = blockIdx.x * (blockDim.x >> 6) + (threadIdx.x >> 6);
    if (r >= nrows) return;
    int lane = threadIdx.x & 63;
    int q = lane >> 4;
    int d8 = lane & 15;

    int2 se = rp2[r];
    int s0 = se.x, e0 = se.y;
    float a0 = 0.f, a1 = 0.f, a2 = 0.f, a3 = 0.f;
    int i = s0;
    for (; i + 32 <= e0; i += 32) {
        uint pe[8];
#pragma unroll
        for (int s = 0; s < 8; ++s)
            pe[s] = csr[i + 4 * s + q];
        uint2 wv[8];
#pragma unroll
        for (int s = 0; s < 8; ++s)
            wv[s] = *(const uint2*)(xb + (((long long)(pe[s] >> 14)) << 5) + 2 * d8);
#pragma unroll
        for (int s = 0; s < 8; ++s) {
            float v = dec14(pe[s] & 0x3FFFu);
            a0 += v * bflo(wv[s].x); a1 += v * bfhi(wv[s].x);
            a2 += v * bflo(wv[s].y); a3 += v * bfhi(wv[s].y);
        }
    }
    for (; i < e0; i += 4) {
        int idx = i + q;
        uint pe = (idx < e0) ? csr[idx] : 0u;
        uint2 wv = *(const uint2*)(xb + (((long long)(pe >> 14)) << 5) + 2 * d8);
        float v = dec14(pe & 0x3FFFu);
        a0 += v * bflo(wv.x); a1 += v * bfhi(wv.x); a2 += v * bflo(wv.y); a3 += v * bfhi(wv.y);
    }
    a0 += __shfl_xor(a0, 16); a0 += __shfl_xor(a0, 32);
    a1 += __shfl_xor(a1, 16); a1 += __shfl_xor(a1, 32);
    a2 += __shfl_xor(a2, 16); a2 += __shfl_xor(a2, 32);
    a3 += __shfl_xor(a3, 16); a3 += __shfl_xor(a3, 32);

    float sq = a0 * a0 + a1 * a1 + a2 * a2 + a3 * a3;
    sq += __shfl_xor(sq, 1); sq += __shfl_xor(sq, 2);
    sq += __shfl_xor(sq, 4); sq += __shfl_xor(sq, 8);
    float inv = 1.0f / fmaxf(sqrtf(sq), 1e-12f);
    if (q == 0) {
        long long off4 = (((long long)r) << 6) + 4 * d8;
        float4 o;
        if (MODE == 2) {
            o.x = a0 * inv; o.y = a1 * inv; o.z = a2 * inv; o.w = a3 * inv;
        } else {
            float4 b4 = *(const float4*)(base + off4);
            o.x = 0.5f * a0 * inv + 0.5f * b4.x;
            o.y = 0.5f * a1 * inv + 0.5f * b4.y;
            o.z = 0.5f * a2 * inv + 0.5f * b4.z;
            o.w = 0.5f * a3 * inv + 0.5f * b4.w;
        }
        *(float4*)(yf + off4) = o;
    }
}

// ---------------- host ----------------

static inline int nblk(long long n, int b) { return (int)((n + b - 1) / b); }
static inline size_t al256(size_t x) { return (x + 255) & ~(size_t)255; }
#define AMAX 7250000   // max arena entries (g0: 782 bins * 9207 cap = 7,199,874)

extern "C" void kernel_launch(void* const* d_in, const int* in_sizes, int n_in,
                              void* d_out, int out_size, void* d_ws, size_t ws_size,
                              hipStream_t stream) {
    const float* emb_user   = (const float*)d_in[0];
    const float* emb_item   = (const float*)d_in[1];
    const float* emb_author = (const float*)d_in[2];
    const int*   g0r = (const int*)d_in[3];
    const int*   g0c = (const int*)d_in[4];
    const float* g0v = (const float*)d_in[5];
    const int*   g1r = (const int*)d_in[6];
    const int*   g1c = (const int*)d_in[7];
    const float* g1v = (const float*)d_in[8];
    const int*   g3r = (const int*)d_in[9];
    const int*   g3c = (const int*)d_in[10];
    const float* g3v = (const float*)d_in[11];
    const int*   g4r = (const int*)d_in[12];
    const int*   g4c = (const int*)d_in[13];
    const float* g4v = (const float*)d_in[14];
    const int*   g5r = (const int*)d_in[15];
    const int*   g5c = (const int*)d_in[16];
    const float* g5v = (const float*)d_in[17];

    const int E0 = in_sizes[3];
    const int E1 = in_sizes[6];
    const int E3 = in_sizes[9];
    const int E4 = in_sizes[12];
    const int E5 = in_sizes[15];

    float* out = (float*)d_out;

    // ---- workspace carve-up ----
    // y1b,y2b,items0b contiguous; build staging arena aliases them (g0 arena 57.6MB
    // <= 64MB; items0b dead during g0 build; later arenas fit in y1b+y2b alone).
    char* w = (char*)d_ws;
    int2* rp2     = (int2*)w; w += al256((size_t)(NN0 + 1) * 8);
    int*  binCur5 = (int*)w;  w += al256((size_t)5 * 1024 * 4);
    uint* csr     = (uint*)w; w += al256((size_t)AMAX * 4);
    uint* embUb   = (uint*)w; w += al256((size_t)NUu * 32 * 4);   // bf16 emb planes lo|hi
    uint* embIb   = (uint*)w; w += al256((size_t)NIi * 32 * 4);
    uint* embAb   = (uint*)w; w += al256((size_t)NAa * 32 * 4);
    uint* y1b     = (uint*)w; w += al256((size_t)NN0 * 32 * 4);   // y1 planes lo|hi
    uint* y2b     = (uint*)w; w += al256((size_t)NN0 * 32 * 4);
    uint* items0b = (uint*)w; w += al256((size_t)NIi * 32 * 4);   // bf16 atom_items0 (full-row)
    float* items0 = (float*)w; w += al256((size_t)NIi * DD * 4);  // fp32 atom_items0
    uint* oAuthNb = (uint*)w; w += al256((size_t)NAa * 32 * 4);   // bf16 non_atom_authors
    int2* stage = (int2*)y1b;     // build staging arena (8B/entry)

    uint* embU_p[2] = { embUb, embUb + (size_t)NUu * 16 };
    uint* embI_p[2] = { embIb, embIb + (size_t)NIi * 16 };
    uint* embA_p[2] = { embAb, embAb + (size_t)NAa * 16 };
    uint* y1_p[2]   = { y1b,  y1b + (size_t)NN0 * 16 };
    uint* y2_p[2]   = { y2b,  y2b + (size_t)NN0 * 16 };

    const int B = 256;

    // per-graph bin geometry: cap = mean + mean/16 + 512 (~11 sigma), <= SEG_CAP
    struct G { int nbins, shift, cap; };
    auto geo = [](int E, int N, int shift) {
        G g;
        g.shift = shift;
        g.nbins = (N + (1 << shift) - 1) >> shift;
        int cap = E / g.nbins + E / (16 * g.nbins) + 512;
        g.cap = cap > SEG_CAP ? SEG_CAP : cap;
        return g;
    };
    G gg0 = geo(E0, NN0, 8), gg1 = geo(E1, NN1, 8), gg3 = geo(E3, NAa, 5),
      gg5 = geo(E5, NIi, 8), gg4 = geo(E4, NIi, 8);

    float* oUserA = out;                            // atom_users
    float* oUserN = out + (long long)NUu * DD;      // non_atom_users
    float* oItemA = out + (long long)200000 * DD;   // atom_items
    float* oItemN = out + (long long)300000 * DD;   // non_atom_items
    float* oAuthA = out + (long long)400000 * DD;   // atom_authors
    float* oAuthN = out + (long long)410000 * DD;   // non_atom_authors

    // ---- embeddings -> bf16 split planes + arena cursor init ----
    k_f2bf3s<<<nblk((long long)(NUu + NIi + NAa) * 16, B), B, 0, stream>>>(
        (const float4*)emb_user, (const float4*)emb_item, (const float4*)emb_author,
        (uint2*)embU_p[0], (uint2*)embU_p[1],
        (uint2*)embI_p[0], (uint2*)embI_p[1],
        (uint2*)embA_p[0], (uint2*)embA_p[1]);
    k_arenainit<<<1, 1024, 0, stream>>>(binCur5,
        gg0.nbins, gg1.nbins, gg3.nbins, gg5.nbins, gg4.nbins,
        gg0.cap, gg1.cap, gg3.cap, gg5.cap, gg4.cap);

    auto build = [&](const int* row, const int* col, const float* val,
                     int E, int N, const G& g, int slot) {
        int* bc = binCur5 + slot * 1024;
        k_part1<<<nblk(E, 1024 * P1_ITER), 1024, 0, stream>>>(row, col, val, bc,
                                                              stage, E, g.shift,
                                                              g.nbins, g.cap);
        k_part2<<<g.nbins, 1024, 0, stream>>>(bc, stage, csr, rp2, N, g.shift, g.cap);
    };

    // 3-layer propagation for one branch, split into two 32-dim planes
    auto propagate = [&](uint* eA_p0, uint* eA_p1, uint* eB_p0, uint* eB_p1,
                         const float* fA, const float* fB,
                         float* oU, float* oI, uint* oIb, int N) {
        uint* eA_p[2] = { eA_p0, eA_p1 };
        uint* eB_p[2] = { eB_p0, eB_p1 };
        for (int p = 0; p < 2; ++p) {
            k_spmmh<0, true><<<nblk(N, 4), B, 0, stream>>>(rp2, csr,
                eA_p[p], eB_p[p], NUu, 32 * p, nullptr, nullptr,
                nullptr, nullptr, nullptr, nullptr, nullptr, y1_p[p], N);
            k_spmmh<0, false><<<nblk(N, 4), B, 0, stream>>>(rp2, csr,
                y1_p[p], nullptr, 0, 32 * p, nullptr, nullptr,
                nullptr, nullptr, nullptr, nullptr, nullptr, y2_p[p], N);
            k_spmmh<1, false><<<nblk(N, 4), B, 0, stream>>>(rp2, csr,
                y2_p[p], nullptr, NUu, 32 * p, fA, fB,
                y1_p[p], y2_p[p], oU, oI, oIb, nullptr, N);
        }
    };

    // ========== atom branch: 3-layer propagate on g0 ==========
    build(g0r, g0c, g0v, E0, NN0, gg0, 0);
    propagate(embU_p[0], embU_p[1], embI_p[0], embI_p[1],
              emb_user, emb_item, oUserA, items0, items0b, NN0);

    // ========== non-atom branch: 3-layer propagate on g1 ==========
    build(g1r, g1c, g1v, E1, NN1, gg1, 1);
    propagate(embU_p[0], embU_p[1], embA_p[0], embA_p[1],
              emb_user, emb_author, oUserN, oAuthN, oAuthNb, NN1);

    // ========== atom_authors = normalize(g3 @ items0) ==========
    build(g3r, g3c, g3v, E3, NAa, gg3, 2);
    k_spmm<2><<<nblk(NAa, 4), B, 0, stream>>>(rp2, csr, items0b, oAuthA, nullptr, NAa);

    // ========== atom_items = 0.5*normalize(g5 @ items0) + 0.5*items0 ==========
    build(g5r, g5c, g5v, E5, NIi, gg5, 3);
    k_spmm<3><<<nblk(NIi, 4), B, 0, stream>>>(rp2, csr, items0b, oItemA, items0, NIi);

    // ========== non_atom_items = normalize(g4 @ non_atom_authors) ==========
    build(g4r, g4c, g4v, E4, NIi, gg4, 4);
    k_spmm<2><<<nblk(NIi, 4), B, 0, stream>>>(rp2, csr, oAuthNb, oItemN, nullptr, NIi);
}

// Round 15
// 1151.909 us; speedup vs baseline: 1.3132x; 1.3132x over previous
//
#include <hip/hip_runtime.h>

#define NUu 100000
#define NIi 100000
#define NAa 10000
#define DD  64
#define NN0 (NUu + NIi)   // 200000
#define NN1 (NUu + NAa)   // 110000

typedef unsigned int uint;
typedef unsigned short ushort;

// ---------------- bf16 / val14 helpers ----------------

__device__ __forceinline__ uint pack_bf2(float x, float y) {
    uint a = __float_as_uint(x);
    uint b = __float_as_uint(y);
    a = (a + 0x7fffu + ((a >> 16) & 1u)) >> 16;          // RNE low half
    b = (b + 0x7fffu + ((b >> 16) & 1u)) & 0xffff0000u;  // RNE high half
    return (a & 0xffffu) | b;
}
__device__ __forceinline__ float bflo(uint w) { return __uint_as_float(w << 16); }
__device__ __forceinline__ float bfhi(uint w) { return __uint_as_float(w & 0xffff0000u); }

// positive val -> 14-bit float (e8m6): bf16 RNE then drop 1 mantissa bit (rounded)
__device__ __forceinline__ uint enc14(float v) {
    uint u = __float_as_uint(v);
    uint bf = (u + 0x7fffu + ((u >> 16) & 1u)) >> 16;
    return ((bf + 1u) >> 1) & 0x3FFFu;
}
__device__ __forceinline__ float dec14(uint e) { return __uint_as_float(e << 17); }

// convert all three embeddings fp32 -> packed bf16x2 in one launch
__global__ void k_f2bf3(const float4* __restrict__ su, const float4* __restrict__ si,
                        const float4* __restrict__ sa,
                        uint2* __restrict__ du, uint2* __restrict__ di,
                        uint2* __restrict__ da) {
    int i = blockIdx.x * blockDim.x + threadIdx.x;
    const int nu = NUu * 16, ni = NIi * 16, na = NAa * 16;
    const float4* s;
    uint2* d;
    int j;
    if (i < nu) { s = su; d = du; j = i; }
    else if (i < nu + ni) { s = si; d = di; j = i - nu; }
    else if (i < nu + ni + na) { s = sa; d = da; j = i - nu - ni; }
    else return;
    float4 v = s[j];
    uint2 o;
    o.x = pack_bf2(v.x, v.y);
    o.y = pack_bf2(v.z, v.w);
    d[j] = o;
}

// ---------------- CSR build (arena bins, single partition pass) ----------------

#define P1_ITER 32        // 16384 edges per 512-thread block -> ~21 edges/bin run
#define SEG_CAP 9472      // max edges per bin

// init all five graphs' bin cursors to b*cap (arena bases); slots of 1024
__global__ void k_arenainit(int* __restrict__ bc,
                            int nb0, int nb1, int nb2, int nb3, int nb4,
                            int c0, int c1, int c2, int c3, int c4) {
    int t = threadIdx.x;
    if (t < nb0) bc[t] = t * c0;
    if (t < nb1) bc[1024 + t] = t * c1;
    if (t < nb2) bc[2048 + t] = t * c2;
    if (t < nb3) bc[3072 + t] = t * c3;
    if (t < nb4) bc[4096 + t] = t * c4;
}

// P1: two-pass over block's edge range (row stream read twice, streaming-cheap):
// LDS bin histogram -> block reservation -> ONE 8B staged write/edge.
// stage = {(rowlow<<18)|col, fp32 val bits}
__global__ void __launch_bounds__(512)
k_part1(const int* __restrict__ row, const int* __restrict__ col,
        const float* __restrict__ val, int* __restrict__ binCur,
        int2* __restrict__ stage, int E, int shift, int nbins, int cap) {
    __shared__ int h[1024];
    for (int t = threadIdx.x; t < nbins; t += blockDim.x) h[t] = 0;
    __syncthreads();
    int e0 = blockIdx.x * (blockDim.x * P1_ITER) + threadIdx.x;
#pragma unroll 4
    for (int i = 0; i < P1_ITER; ++i) {
        int e = e0 + i * blockDim.x;
        if (e < E) atomicAdd(&h[row[e] >> shift], 1);
    }
    __syncthreads();
    for (int t = threadIdx.x; t < nbins; t += blockDim.x) {
        int c = h[t];
        h[t] = c ? atomicAdd(binCur + t, c) : 0;
    }
    __syncthreads();
#pragma unroll 4
    for (int i = 0; i < P1_ITER; ++i) {
        int e = e0 + i * blockDim.x;
        if (e < E) {
            int rr = row[e];
            int b = rr >> shift;
            int pos = atomicAdd(&h[b], 1);
            if (pos < (b + 1) * cap) {            // arena overflow guard (~11 sigma)
                int2 p;
                p.x = ((rr & ((1 << shift) - 1)) << 18) | col[e];
                p.y = __float_as_int(val[e]);
                stage[pos] = p;
            }
        }
    }
}

// P2: one block per bin. LDS-stage segment once, per-row count+scan -> rp2{start,end},
// then exact placement writing the 4B packed payload (col<<14)|enc14(val).
__global__ void __launch_bounds__(1024)
k_part2(const int* __restrict__ binCur, const int2* __restrict__ stage,
        uint* __restrict__ csr, int2* __restrict__ rp2, int N, int shift, int cap) {
    __shared__ int2 seg[SEG_CAP];
    __shared__ int h[512];
    __shared__ int s[512];
    int tid = threadIdx.x;
    int rbase = blockIdx.x << shift;
    int nr = min(1 << shift, N - rbase);
    int es = blockIdx.x * cap;
    int ee = min(binCur[blockIdx.x], es + cap);
    int n = ee - es;                              // n <= cap <= SEG_CAP
    if (tid < 512) h[tid] = 0;
    for (int i = tid; i < n; i += blockDim.x) seg[i] = stage[es + i];
    __syncthreads();
    for (int i = tid; i < n; i += blockDim.x)
        atomicAdd(&h[seg[i].x >> 18], 1);
    __syncthreads();
    int v = (tid < 512) ? h[tid] : 0;
    if (tid < 512) s[tid] = v;
    __syncthreads();
    for (int off = 1; off < 512; off <<= 1) {
        int t = (tid < 512 && tid >= off) ? s[tid - off] : 0;
        __syncthreads();
        if (tid < 512) s[tid] += t;
        __syncthreads();
    }
    if (tid < 512) h[tid] = es + s[tid] - v;      // row cursor
    if (tid < nr) {
        int st = es + s[tid] - v;
        rp2[rbase + tid] = make_int2(st, st + v);
    }
    __syncthreads();
    for (int i = tid; i < n; i += blockDim.x) {
        int2 p = seg[i];
        int pos = atomicAdd(&h[p.x >> 18], 1);
        csr[pos] = (((uint)(p.x & 0x3ffff)) << 14) | enc14(__int_as_float(p.y));
    }
}

// ---------------- SpMM (bf16 gather, one wave = one row, quarter-wave/edge) ----------------
// payload pe: col = pe>>14, val = dec14(pe & 0x3FFF)
// lane = q*16 + d8 ; quarter q owns one edge slot; lane reads uint2 = dims 4*d8..4*d8+3.

template <bool SS>
__device__ __forceinline__ const uint* gb(uint pe, const uint* xbA, const uint* xbB,
                                          int split) {
    int c = (int)(pe >> 14);
    if (SS) return (c < split) ? xbA + (((long long)c) << 5)
                               : xbB + (((long long)(c - split)) << 5);
    return xbA + (((long long)c) << 5);
}

// MODE 0: plain  — ob = pack(a)
// MODE 1: final  — out = 0.25*(emb + y1 + y2 + a); fp32 out split U/I, optional bf16 outIb
// MODE 2: norm   — yf = normalize(a)
// MODE 3: blend  — yf = 0.5*normalize(a) + 0.5*base
template <int MODE, bool SS>
__global__ void k_spmm(const int2* __restrict__ rp2, const uint* __restrict__ csr,
                       const uint* __restrict__ xbA, const uint* __restrict__ xbB, int split,
                       const float* __restrict__ embA, const float* __restrict__ embB,
                       const uint* __restrict__ y1b, const uint* __restrict__ y2b,
                       float* __restrict__ outU, float* __restrict__ outI,
                       uint* __restrict__ outIb,
                       uint* __restrict__ ob, float* __restrict__ yf,
                       const float* __restrict__ base, int nrows) {
    int r = blockIdx.x * (blockDim.x >> 6) + (threadIdx.x >> 6);
    if (r >= nrows) return;
    int lane = threadIdx.x & 63;
    int q = lane >> 4;        // edge slot within group of 4
    int d8 = lane & 15;       // covers dims 4*d8 .. 4*d8+3

    int2 se = rp2[r];
    int s0 = se.x, e0 = se.y;
    float a0 = 0.f, a1 = 0.f, a2 = 0.f, a3 = 0.f;
    int i = s0;
    for (; i + 32 <= e0; i += 32) {
        uint pe[8];
#pragma unroll
        for (int s = 0; s < 8; ++s)
            pe[s] = csr[i + 4 * s + q];
        uint2 wv[8];
#pragma unroll
        for (int s = 0; s < 8; ++s)
            wv[s] = *(const uint2*)(gb<SS>(pe[s], xbA, xbB, split) + 2 * d8);
#pragma unroll
        for (int s = 0; s < 8; ++s) {
            float v = dec14(pe[s] & 0x3FFFu);
            a0 += v * bflo(wv[s].x); a1 += v * bfhi(wv[s].x);
            a2 += v * bflo(wv[s].y); a3 += v * bfhi(wv[s].y);
        }
    }
    for (; i + 8 <= e0; i += 8) {
        uint p0 = csr[i + q];
        uint p1 = csr[i + 4 + q];
        uint2 w0 = *(const uint2*)(gb<SS>(p0, xbA, xbB, split) + 2 * d8);
        uint2 w1 = *(const uint2*)(gb<SS>(p1, xbA, xbB, split) + 2 * d8);
        float v0 = dec14(p0 & 0x3FFFu);
        float v1 = dec14(p1 & 0x3FFFu);
        a0 += v0 * bflo(w0.x); a1 += v0 * bfhi(w0.x);
        a2 += v0 * bflo(w0.y); a3 += v0 * bfhi(w0.y);
        a0 += v1 * bflo(w1.x); a1 += v1 * bfhi(w1.x);
        a2 += v1 * bflo(w1.y); a3 += v1 * bfhi(w1.y);
    }
    for (; i < e0; i += 4) {
        int idx = i + q;
        uint pe = (idx < e0) ? csr[idx] : 0u;    // col 0, val 0 pad
        uint2 wv = *(const uint2*)(gb<SS>(pe, xbA, xbB, split) + 2 * d8);
        float v = dec14(pe & 0x3FFFu);
        a0 += v * bflo(wv.x); a1 += v * bfhi(wv.x); a2 += v * bflo(wv.y); a3 += v * bfhi(wv.y);
    }
    // reduce across the 4 quarters (lanes with equal d8)
    a0 += __shfl_xor(a0, 16); a0 += __shfl_xor(a0, 32);
    a1 += __shfl_xor(a1, 16); a1 += __shfl_xor(a1, 32);
    a2 += __shfl_xor(a2, 16); a2 += __shfl_xor(a2, 32);
    a3 += __shfl_xor(a3, 16); a3 += __shfl_xor(a3, 32);

    long long off4 = (((long long)r) << 6) + 4 * d8;     // float index of dim 4*d8
    long long offw = (((long long)r) << 5) + 2 * d8;     // uint index

    if (MODE == 0) {
        if (q == 0) {
            uint2 o;
            o.x = pack_bf2(a0, a1);
            o.y = pack_bf2(a2, a3);
            *(uint2*)(ob + offw) = o;
        }
    } else if (MODE == 1) {
        if (q == 0) {
            float4 e4;
            if (r < split) e4 = *(const float4*)(embA + off4);
            else           e4 = *(const float4*)(embB + (off4 - (((long long)split) << 6)));
            uint2 w1 = *(const uint2*)(y1b + offw);
            uint2 w2 = *(const uint2*)(y2b + offw);
            float s0f = 0.25f * (e4.x + bflo(w1.x) + bflo(w2.x) + a0);
            float s1f = 0.25f * (e4.y + bfhi(w1.x) + bfhi(w2.x) + a1);
            float s2f = 0.25f * (e4.z + bflo(w1.y) + bflo(w2.y) + a2);
            float s3f = 0.25f * (e4.w + bfhi(w1.y) + bfhi(w2.y) + a3);
            float4 o;
            o.x = s0f; o.y = s1f; o.z = s2f; o.w = s3f;
            if (r < split) {
                *(float4*)(outU + off4) = o;
            } else {
                *(float4*)(outI + (off4 - (((long long)split) << 6))) = o;
                if (outIb) {
                    uint2 ob2;
                    ob2.x = pack_bf2(s0f, s1f);
                    ob2.y = pack_bf2(s2f, s3f);
                    *(uint2*)(outIb + (((long long)(r - split)) << 5) + 2 * d8) = ob2;
                }
            }
        }
    } else {
        float sq = a0 * a0 + a1 * a1 + a2 * a2 + a3 * a3;
        sq += __shfl_xor(sq, 1); sq += __shfl_xor(sq, 2);
        sq += __shfl_xor(sq, 4); sq += __shfl_xor(sq, 8);
        float inv = 1.0f / fmaxf(sqrtf(sq), 1e-12f);
        if (q == 0) {
            float4 o;
            if (MODE == 2) {
                o.x = a0 * inv; o.y = a1 * inv; o.z = a2 * inv; o.w = a3 * inv;
            } else {
                float4 b4 = *(const float4*)(base + off4);
                o.x = 0.5f * a0 * inv + 0.5f * b4.x;
                o.y = 0.5f * a1 * inv + 0.5f * b4.y;
                o.z = 0.5f * a2 * inv + 0.5f * b4.z;
                o.w = 0.5f * a3 * inv + 0.5f * b4.w;
            }
            *(float4*)(yf + off4) = o;
        }
    }
}

// ---------------- host ----------------

static inline int nblk(long long n, int b) { return (int)((n + b - 1) / b); }
static inline size_t al256(size_t x) { return (x + 255) & ~(size_t)255; }
#define AMAX 7250000   // max arena entries (g0: 782 bins * 9207 cap = 7,199,874)

extern "C" void kernel_launch(void* const* d_in, const int* in_sizes, int n_in,
                              void* d_out, int out_size, void* d_ws, size_t ws_size,
                              hipStream_t stream) {
    const float* emb_user   = (const float*)d_in[0];
    const float* emb_item   = (const float*)d_in[1];
    const float* emb_author = (const float*)d_in[2];
    const int*   g0r = (const int*)d_in[3];
    const int*   g0c = (const int*)d_in[4];
    const float* g0v = (const float*)d_in[5];
    const int*   g1r = (const int*)d_in[6];
    const int*   g1c = (const int*)d_in[7];
    const float* g1v = (const float*)d_in[8];
    const int*   g3r = (const int*)d_in[9];
    const int*   g3c = (const int*)d_in[10];
    const float* g3v = (const float*)d_in[11];
    const int*   g4r = (const int*)d_in[12];
    const int*   g4c = (const int*)d_in[13];
    const float* g4v = (const float*)d_in[14];
    const int*   g5r = (const int*)d_in[15];
    const int*   g5c = (const int*)d_in[16];
    const float* g5v = (const float*)d_in[17];

    const int E0 = in_sizes[3];
    const int E1 = in_sizes[6];
    const int E3 = in_sizes[9];
    const int E4 = in_sizes[12];
    const int E5 = in_sizes[15];

    float* out = (float*)d_out;

    // ---- workspace carve-up ----
    // y1b,y2b,items0b contiguous; build staging arena aliases them (g0 arena 57.6MB
    // <= 64MB; items0b dead during g0 build; later arenas fit in y1b+y2b alone).
    char* w = (char*)d_ws;
    int2* rp2     = (int2*)w; w += al256((size_t)(NN0 + 1) * 8);
    int*  binCur5 = (int*)w;  w += al256((size_t)5 * 1024 * 4);
    uint* csr     = (uint*)w; w += al256((size_t)AMAX * 4);
    uint* embUb   = (uint*)w; w += al256((size_t)NUu * 32 * 4);   // bf16 embeddings
    uint* embIb   = (uint*)w; w += al256((size_t)NIi * 32 * 4);
    uint* embAb   = (uint*)w; w += al256((size_t)NAa * 32 * 4);
    uint* y1b     = (uint*)w; w += al256((size_t)NN0 * 32 * 4);   // bf16 layer outs
    uint* y2b     = (uint*)w; w += al256((size_t)NN0 * 32 * 4);
    uint* items0b = (uint*)w; w += al256((size_t)NIi * 32 * 4);   // bf16 atom_items0
    float* items0 = (float*)w; w += al256((size_t)NIi * DD * 4);  // fp32 atom_items0
    uint* oAuthNb = (uint*)w; w += al256((size_t)NAa * 32 * 4);   // bf16 non_atom_authors
    int2* stage = (int2*)y1b;     // build staging arena (8B/entry)

    const int B = 256;

    // per-graph bin geometry: cap = mean + mean/16 + 512 (~11 sigma), <= SEG_CAP
    struct G { int nbins, shift, cap; };
    auto geo = [](int E, int N, int shift) {
        G g;
        g.shift = shift;
        g.nbins = (N + (1 << shift) - 1) >> shift;
        int cap = E / g.nbins + E / (16 * g.nbins) + 512;
        g.cap = cap > SEG_CAP ? SEG_CAP : cap;
        return g;
    };
    G gg0 = geo(E0, NN0, 8), gg1 = geo(E1, NN1, 8), gg3 = geo(E3, NAa, 5),
      gg5 = geo(E5, NIi, 8), gg4 = geo(E4, NIi, 8);

    float* oUserA = out;                            // atom_users
    float* oUserN = out + (long long)NUu * DD;      // non_atom_users
    float* oItemA = out + (long long)200000 * DD;   // atom_items
    float* oItemN = out + (long long)300000 * DD;   // non_atom_items
    float* oAuthA = out + (long long)400000 * DD;   // atom_authors
    float* oAuthN = out + (long long)410000 * DD;   // non_atom_authors

    // ---- embeddings -> bf16 (one launch) + arena cursor init (one launch) ----
    k_f2bf3<<<nblk((long long)(NUu + NIi + NAa) * 16, B), B, 0, stream>>>(
        (const float4*)emb_user, (const float4*)emb_item, (const float4*)emb_author,
        (uint2*)embUb, (uint2*)embIb, (uint2*)embAb);
    k_arenainit<<<1, 1024, 0, stream>>>(binCur5,
        gg0.nbins, gg1.nbins, gg3.nbins, gg5.nbins, gg4.nbins,
        gg0.cap, gg1.cap, gg3.cap, gg5.cap, gg4.cap);

    auto build = [&](const int* row, const int* col, const float* val,
                     int E, int N, const G& g, int slot) {
        int* bc = binCur5 + slot * 1024;
        k_part1<<<nblk(E, 512 * P1_ITER), 512, 0, stream>>>(row, col, val, bc,
                                                            stage, E, g.shift,
                                                            g.nbins, g.cap);
        k_part2<<<g.nbins, 1024, 0, stream>>>(bc, stage, csr, rp2, N, g.shift, g.cap);
    };

    // ========== atom branch: 3-layer propagate on g0 ==========
    build(g0r, g0c, g0v, E0, NN0, gg0, 0);
    k_spmm<0, true><<<nblk(NN0, 4), B, 0, stream>>>(rp2, csr, embUb, embIb, NUu,
                                                    nullptr, nullptr, nullptr, nullptr,
                                                    nullptr, nullptr, nullptr,
                                                    y1b, nullptr, nullptr, NN0);
    k_spmm<0, false><<<nblk(NN0, 4), B, 0, stream>>>(rp2, csr, y1b, nullptr, 0,
                                                     nullptr, nullptr, nullptr, nullptr,
                                                     nullptr, nullptr, nullptr,
                                                     y2b, nullptr, nullptr, NN0);
    k_spmm<1, false><<<nblk(NN0, 4), B, 0, stream>>>(rp2, csr, y2b, nullptr, NUu,
                                                     emb_user, emb_item, y1b, y2b,
                                                     oUserA, items0, items0b,
                                                     nullptr, nullptr, nullptr, NN0);

    // ========== non-atom branch: 3-layer propagate on g1 ==========
    build(g1r, g1c, g1v, E1, NN1, gg1, 1);
    k_spmm<0, true><<<nblk(NN1, 4), B, 0, stream>>>(rp2, csr, embUb, embAb, NUu,
                                                    nullptr, nullptr, nullptr, nullptr,
                                                    nullptr, nullptr, nullptr,
                                                    y1b, nullptr, nullptr, NN1);
    k_spmm<0, false><<<nblk(NN1, 4), B, 0, stream>>>(rp2, csr, y1b, nullptr, 0,
                                                     nullptr, nullptr, nullptr, nullptr,
                                                     nullptr, nullptr, nullptr,
                                                     y2b, nullptr, nullptr, NN1);
    k_spmm<1, false><<<nblk(NN1, 4), B, 0, stream>>>(rp2, csr, y2b, nullptr, NUu,
                                                     emb_user, emb_author, y1b, y2b,
                                                     oUserN, oAuthN, oAuthNb,
                                                     nullptr, nullptr, nullptr, NN1);

    // ========== atom_authors = normalize(g3 @ items0) ==========
    build(g3r, g3c, g3v, E3, NAa, gg3, 2);
    k_spmm<2, false><<<nblk(NAa, 4), B, 0, stream>>>(rp2, csr, items0b, nullptr, 0,
                                                     nullptr, nullptr, nullptr, nullptr,
                                                     nullptr, nullptr, nullptr,
                                                     nullptr, oAuthA, nullptr, NAa);

    // ========== atom_items = 0.5*normalize(g5 @ items0) + 0.5*items0 ==========
    build(g5r, g5c, g5v, E5, NIi, gg5, 3);
    k_spmm<3, false><<<nblk(NIi, 4), B, 0, stream>>>(rp2, csr, items0b, nullptr, 0,
                                                     nullptr, nullptr, nullptr, nullptr,
                                                     nullptr, nullptr, nullptr,
                                                     nullptr, oItemA, items0, NIi);

    // ========== non_atom_items = normalize(g4 @ non_atom_authors) ==========
    build(g4r, g4c, g4v, E4, NIi, gg4, 4);
    k_spmm<2, false><<<nblk(NIi, 4), B, 0, stream>>>(rp2, csr, oAuthNb, nullptr, 0,
                                                     nullptr, nullptr, nullptr, nullptr,
                                                     nullptr, nullptr, nullptr,
                                                     nullptr, oItemN, nullptr, NIi);
}

// Round 16
// 1075.461 us; speedup vs baseline: 1.4065x; 1.0711x over previous
//
#include <hip/hip_runtime.h>

#define NUu 100000
#define NIi 100000
#define NAa 10000
#define DD  64
#define NN0 (NUu + NIi)   // 200000
#define NN1 (NUu + NAa)   // 110000

typedef unsigned int uint;
typedef unsigned short ushort;

// ---------------- bf16 / val14 helpers ----------------

__device__ __forceinline__ uint pack_bf2(float x, float y) {
    uint a = __float_as_uint(x);
    uint b = __float_as_uint(y);
    a = (a + 0x7fffu + ((a >> 16) & 1u)) >> 16;          // RNE low half
    b = (b + 0x7fffu + ((b >> 16) & 1u)) & 0xffff0000u;  // RNE high half
    return (a & 0xffffu) | b;
}
__device__ __forceinline__ float bflo(uint w) { return __uint_as_float(w << 16); }
__device__ __forceinline__ float bfhi(uint w) { return __uint_as_float(w & 0xffff0000u); }

// positive val -> 14-bit float (e8m6): bf16 RNE then drop 1 mantissa bit (rounded)
__device__ __forceinline__ uint enc14(float v) {
    uint u = __float_as_uint(v);
    uint bf = (u + 0x7fffu + ((u >> 16) & 1u)) >> 16;
    return ((bf + 1u) >> 1) & 0x3FFFu;
}
__device__ __forceinline__ float dec14(uint e) { return __uint_as_float(e << 17); }

// convert all three embeddings fp32 -> packed bf16x2 in one launch
__global__ void k_f2bf3(const float4* __restrict__ su, const float4* __restrict__ si,
                        const float4* __restrict__ sa,
                        uint2* __restrict__ du, uint2* __restrict__ di,
                        uint2* __restrict__ da) {
    int i = blockIdx.x * blockDim.x + threadIdx.x;
    const int nu = NUu * 16, ni = NIi * 16, na = NAa * 16;
    const float4* s;
    uint2* d;
    int j;
    if (i < nu) { s = su; d = du; j = i; }
    else if (i < nu + ni) { s = si; d = di; j = i - nu; }
    else if (i < nu + ni + na) { s = sa; d = da; j = i - nu - ni; }
    else return;
    float4 v = s[j];
    uint2 o;
    o.x = pack_bf2(v.x, v.y);
    o.y = pack_bf2(v.z, v.w);
    d[j] = o;
}

// ---------------- CSR build (arena bins, single partition pass) ----------------

#define P1_ITER 8
#define SEG_CAP 9472      // max edges per bin (LDS: 8B*9472 + 4KB = 79.8KB -> 2 blk/CU)

// init all five graphs' bin cursors to b*cap (arena bases); slots of 1024
__global__ void k_arenainit(int* __restrict__ bc,
                            int nb0, int nb1, int nb2, int nb3, int nb4,
                            int c0, int c1, int c2, int c3, int c4) {
    int t = threadIdx.x;
    if (t < nb0) bc[t] = t * c0;
    if (t < nb1) bc[1024 + t] = t * c1;
    if (t < nb2) bc[2048 + t] = t * c2;
    if (t < nb3) bc[3072 + t] = t * c3;
    if (t < nb4) bc[4096 + t] = t * c4;
}

// P1: single pass — LDS bin histogram -> block reservation -> ONE 8B staged write/edge.
// stage = {(rowlow<<18)|col, fp32 val bits}
__global__ void __launch_bounds__(1024)
k_part1(const int* __restrict__ row, const int* __restrict__ col,
        const float* __restrict__ val, int* __restrict__ binCur,
        int2* __restrict__ stage, int E, int shift, int nbins, int cap) {
    __shared__ int h[1024];
    for (int t = threadIdx.x; t < nbins; t += blockDim.x) h[t] = 0;
    __syncthreads();
    int e0 = blockIdx.x * (blockDim.x * P1_ITER) + threadIdx.x;
    int r[P1_ITER];
#pragma unroll
    for (int i = 0; i < P1_ITER; ++i) {
        int e = e0 + i * blockDim.x;
        r[i] = (e < E) ? row[e] : -1;
        if (r[i] >= 0) atomicAdd(&h[r[i] >> shift], 1);
    }
    __syncthreads();
    for (int t = threadIdx.x; t < nbins; t += blockDim.x) {
        int c = h[t];
        h[t] = c ? atomicAdd(binCur + t, c) : 0;
    }
    __syncthreads();
#pragma unroll
    for (int i = 0; i < P1_ITER; ++i) {
        int e = e0 + i * blockDim.x;
        if (e < E) {
            int rr = r[i];
            int b = rr >> shift;
            int pos = atomicAdd(&h[b], 1);
            if (pos < (b + 1) * cap) {            // arena overflow guard (~11 sigma)
                int2 p;
                p.x = ((rr & ((1 << shift) - 1)) << 18) | col[e];
                p.y = __float_as_int(val[e]);
                stage[pos] = p;
            }
        }
    }
}

// P2: one block per bin. LDS-stage segment once, per-row count+scan -> rp2{start,end},
// then exact placement writing the 4B packed payload (col<<14)|enc14(val).
__global__ void __launch_bounds__(1024)
k_part2(const int* __restrict__ binCur, const int2* __restrict__ stage,
        uint* __restrict__ csr, int2* __restrict__ rp2, int N, int shift, int cap) {
    __shared__ int2 seg[SEG_CAP];
    __shared__ int h[512];
    __shared__ int s[512];
    int tid = threadIdx.x;
    int rbase = blockIdx.x << shift;
    int nr = min(1 << shift, N - rbase);
    int es = blockIdx.x * cap;
    int ee = min(binCur[blockIdx.x], es + cap);
    int n = ee - es;                              // n <= cap <= SEG_CAP
    if (tid < 512) h[tid] = 0;
    for (int i = tid; i < n; i += blockDim.x) seg[i] = stage[es + i];
    __syncthreads();
    for (int i = tid; i < n; i += blockDim.x)
        atomicAdd(&h[seg[i].x >> 18], 1);
    __syncthreads();
    int v = (tid < 512) ? h[tid] : 0;
    if (tid < 512) s[tid] = v;
    __syncthreads();
    for (int off = 1; off < 512; off <<= 1) {
        int t = (tid < 512 && tid >= off) ? s[tid - off] : 0;
        __syncthreads();
        if (tid < 512) s[tid] += t;
        __syncthreads();
    }
    if (tid < 512) h[tid] = es + s[tid] - v;      // row cursor
    if (tid < nr) {
        int st = es + s[tid] - v;
        rp2[rbase + tid] = make_int2(st, st + v);
    }
    __syncthreads();
    for (int i = tid; i < n; i += blockDim.x) {
        int2 p = seg[i];
        int pos = atomicAdd(&h[p.x >> 18], 1);
        csr[pos] = (((uint)(p.x & 0x3ffff)) << 14) | enc14(__int_as_float(p.y));
    }
}

// ---------------- SpMM (bf16 gather, one wave = one row, quarter-wave/edge) ----------------
// payload pe: col = pe>>14, val = dec14(pe & 0x3FFF)
// lane = q*16 + d8 ; quarter q owns one edge slot; lane reads uint2 = dims 4*d8..4*d8+3.

template <bool SS>
__device__ __forceinline__ const uint* gb(uint pe, const uint* xbA, const uint* xbB,
                                          int split) {
    int c = (int)(pe >> 14);
    if (SS) return (c < split) ? xbA + (((long long)c) << 5)
                               : xbB + (((long long)(c - split)) << 5);
    return xbA + (((long long)c) << 5);
}

// MODE 0: plain  — ob = pack(a)
// MODE 1: final  — out = 0.25*(emb + y1 + y2 + a); fp32 out split U/I, optional bf16 outIb
// MODE 2: norm   — yf = normalize(a)
// MODE 3: blend  — yf = 0.5*normalize(a) + 0.5*base
template <int MODE, bool SS>
__global__ void k_spmm(const int2* __restrict__ rp2, const uint* __restrict__ csr,
                       const uint* __restrict__ xbA, const uint* __restrict__ xbB, int split,
                       const float* __restrict__ embA, const float* __restrict__ embB,
                       const uint* __restrict__ y1b, const uint* __restrict__ y2b,
                       float* __restrict__ outU, float* __restrict__ outI,
                       uint* __restrict__ outIb,
                       uint* __restrict__ ob, float* __restrict__ yf,
                       const float* __restrict__ base, int nrows) {
    int r = blockIdx.x * (blockDim.x >> 6) + (threadIdx.x >> 6);
    if (r >= nrows) return;
    int lane = threadIdx.x & 63;
    int q = lane >> 4;        // edge slot within group of 4
    int d8 = lane & 15;       // covers dims 4*d8 .. 4*d8+3

    int2 se = rp2[r];
    int s0 = se.x, e0 = se.y;
    float a0 = 0.f, a1 = 0.f, a2 = 0.f, a3 = 0.f;
    int i = s0;
    for (; i + 32 <= e0; i += 32) {
        uint pe[8];
#pragma unroll
        for (int s = 0; s < 8; ++s)
            pe[s] = csr[i + 4 * s + q];
        uint2 wv[8];
#pragma unroll
        for (int s = 0; s < 8; ++s)
            wv[s] = *(const uint2*)(gb<SS>(pe[s], xbA, xbB, split) + 2 * d8);
#pragma unroll
        for (int s = 0; s < 8; ++s) {
            float v = dec14(pe[s] & 0x3FFFu);
            a0 += v * bflo(wv[s].x); a1 += v * bfhi(wv[s].x);
            a2 += v * bflo(wv[s].y); a3 += v * bfhi(wv[s].y);
        }
    }
    for (; i + 8 <= e0; i += 8) {
        uint p0 = csr[i + q];
        uint p1 = csr[i + 4 + q];
        uint2 w0 = *(const uint2*)(gb<SS>(p0, xbA, xbB, split) + 2 * d8);
        uint2 w1 = *(const uint2*)(gb<SS>(p1, xbA, xbB, split) + 2 * d8);
        float v0 = dec14(p0 & 0x3FFFu);
        float v1 = dec14(p1 & 0x3FFFu);
        a0 += v0 * bflo(w0.x); a1 += v0 * bfhi(w0.x);
        a2 += v0 * bflo(w0.y); a3 += v0 * bfhi(w0.y);
        a0 += v1 * bflo(w1.x); a1 += v1 * bfhi(w1.x);
        a2 += v1 * bflo(w1.y); a3 += v1 * bfhi(w1.y);
    }
    for (; i < e0; i += 4) {
        int idx = i + q;
        uint pe = (idx < e0) ? csr[idx] : 0u;    // col 0, val 0 pad
        uint2 wv = *(const uint2*)(gb<SS>(pe, xbA, xbB, split) + 2 * d8);
        float v = dec14(pe & 0x3FFFu);
        a0 += v * bflo(wv.x); a1 += v * bfhi(wv.x); a2 += v * bflo(wv.y); a3 += v * bfhi(wv.y);
    }
    // reduce across the 4 quarters (lanes with equal d8)
    a0 += __shfl_xor(a0, 16); a0 += __shfl_xor(a0, 32);
    a1 += __shfl_xor(a1, 16); a1 += __shfl_xor(a1, 32);
    a2 += __shfl_xor(a2, 16); a2 += __shfl_xor(a2, 32);
    a3 += __shfl_xor(a3, 16); a3 += __shfl_xor(a3, 32);

    long long off4 = (((long long)r) << 6) + 4 * d8;     // float index of dim 4*d8
    long long offw = (((long long)r) << 5) + 2 * d8;     // uint index

    if (MODE == 0) {
        if (q == 0) {
            uint2 o;
            o.x = pack_bf2(a0, a1);
            o.y = pack_bf2(a2, a3);
            *(uint2*)(ob + offw) = o;
        }
    } else if (MODE == 1) {
        if (q == 0) {
            float4 e4;
            if (r < split) e4 = *(const float4*)(embA + off4);
            else           e4 = *(const float4*)(embB + (off4 - (((long long)split) << 6)));
            uint2 w1 = *(const uint2*)(y1b + offw);
            uint2 w2 = *(const uint2*)(y2b + offw);
            float s0f = 0.25f * (e4.x + bflo(w1.x) + bflo(w2.x) + a0);
            float s1f = 0.25f * (e4.y + bfhi(w1.x) + bfhi(w2.x) + a1);
            float s2f = 0.25f * (e4.z + bflo(w1.y) + bflo(w2.y) + a2);
            float s3f = 0.25f * (e4.w + bfhi(w1.y) + bfhi(w2.y) + a3);
            float4 o;
            o.x = s0f; o.y = s1f; o.z = s2f; o.w = s3f;
            if (r < split) {
                *(float4*)(outU + off4) = o;
            } else {
                *(float4*)(outI + (off4 - (((long long)split) << 6))) = o;
                if (outIb) {
                    uint2 ob2;
                    ob2.x = pack_bf2(s0f, s1f);
                    ob2.y = pack_bf2(s2f, s3f);
                    *(uint2*)(outIb + (((long long)(r - split)) << 5) + 2 * d8) = ob2;
                }
            }
        }
    } else {
        float sq = a0 * a0 + a1 * a1 + a2 * a2 + a3 * a3;
        sq += __shfl_xor(sq, 1); sq += __shfl_xor(sq, 2);
        sq += __shfl_xor(sq, 4); sq += __shfl_xor(sq, 8);
        float inv = 1.0f / fmaxf(sqrtf(sq), 1e-12f);
        if (q == 0) {
            float4 o;
            if (MODE == 2) {
                o.x = a0 * inv; o.y = a1 * inv; o.z = a2 * inv; o.w = a3 * inv;
            } else {
                float4 b4 = *(const float4*)(base + off4);
                o.x = 0.5f * a0 * inv + 0.5f * b4.x;
                o.y = 0.5f * a1 * inv + 0.5f * b4.y;
                o.z = 0.5f * a2 * inv + 0.5f * b4.z;
                o.w = 0.5f * a3 * inv + 0.5f * b4.w;
            }
            *(float4*)(yf + off4) = o;
        }
    }
}

// ---------------- host ----------------

static inline int nblk(long long n, int b) { return (int)((n + b - 1) / b); }
static inline size_t al256(size_t x) { return (x + 255) & ~(size_t)255; }
#define AMAX 7250000   // max arena entries (g0: 782 bins * 9207 cap = 7,199,874)

extern "C" void kernel_launch(void* const* d_in, const int* in_sizes, int n_in,
                              void* d_out, int out_size, void* d_ws, size_t ws_size,
                              hipStream_t stream) {
    const float* emb_user   = (const float*)d_in[0];
    const float* emb_item   = (const float*)d_in[1];
    const float* emb_author = (const float*)d_in[2];
    const int*   g0r = (const int*)d_in[3];
    const int*   g0c = (const int*)d_in[4];
    const float* g0v = (const float*)d_in[5];
    const int*   g1r = (const int*)d_in[6];
    const int*   g1c = (const int*)d_in[7];
    const float* g1v = (const float*)d_in[8];
    const int*   g3r = (const int*)d_in[9];
    const int*   g3c = (const int*)d_in[10];
    const float* g3v = (const float*)d_in[11];
    const int*   g4r = (const int*)d_in[12];
    const int*   g4c = (const int*)d_in[13];
    const float* g4v = (const float*)d_in[14];
    const int*   g5r = (const int*)d_in[15];
    const int*   g5c = (const int*)d_in[16];
    const float* g5v = (const float*)d_in[17];

    const int E0 = in_sizes[3];
    const int E1 = in_sizes[6];
    const int E3 = in_sizes[9];
    const int E4 = in_sizes[12];
    const int E5 = in_sizes[15];

    float* out = (float*)d_out;

    // ---- workspace carve-up ----
    // y1b,y2b,items0b contiguous; build staging arena aliases them (g0 arena 57.6MB
    // <= 64MB; items0b dead during g0 build; later arenas fit in y1b+y2b alone).
    char* w = (char*)d_ws;
    int2* rp2     = (int2*)w; w += al256((size_t)(NN0 + 1) * 8);
    int*  binCur5 = (int*)w;  w += al256((size_t)5 * 1024 * 4);
    uint* csr     = (uint*)w; w += al256((size_t)AMAX * 4);
    uint* embUb   = (uint*)w; w += al256((size_t)NUu * 32 * 4);   // bf16 embeddings
    uint* embIb   = (uint*)w; w += al256((size_t)NIi * 32 * 4);
    uint* embAb   = (uint*)w; w += al256((size_t)NAa * 32 * 4);
    uint* y1b     = (uint*)w; w += al256((size_t)NN0 * 32 * 4);   // bf16 layer outs
    uint* y2b     = (uint*)w; w += al256((size_t)NN0 * 32 * 4);
    uint* items0b = (uint*)w; w += al256((size_t)NIi * 32 * 4);   // bf16 atom_items0
    float* items0 = (float*)w; w += al256((size_t)NIi * DD * 4);  // fp32 atom_items0
    uint* oAuthNb = (uint*)w; w += al256((size_t)NAa * 32 * 4);   // bf16 non_atom_authors
    int2* stage = (int2*)y1b;     // build staging arena (8B/entry)

    const int B = 256;

    // per-graph bin geometry: cap = mean + mean/16 + 512 (~11 sigma), <= SEG_CAP
    struct G { int nbins, shift, cap; };
    auto geo = [](int E, int N, int shift) {
        G g;
        g.shift = shift;
        g.nbins = (N + (1 << shift) - 1) >> shift;
        int cap = E / g.nbins + E / (16 * g.nbins) + 512;
        g.cap = cap > SEG_CAP ? SEG_CAP : cap;
        return g;
    };
    G gg0 = geo(E0, NN0, 8), gg1 = geo(E1, NN1, 8), gg3 = geo(E3, NAa, 5),
      gg5 = geo(E5, NIi, 8), gg4 = geo(E4, NIi, 8);

    float* oUserA = out;                            // atom_users
    float* oUserN = out + (long long)NUu * DD;      // non_atom_users
    float* oItemA = out + (long long)200000 * DD;   // atom_items
    float* oItemN = out + (long long)300000 * DD;   // non_atom_items
    float* oAuthA = out + (long long)400000 * DD;   // atom_authors
    float* oAuthN = out + (long long)410000 * DD;   // non_atom_authors

    // ---- embeddings -> bf16 (one launch) + arena cursor init (one launch) ----
    k_f2bf3<<<nblk((long long)(NUu + NIi + NAa) * 16, B), B, 0, stream>>>(
        (const float4*)emb_user, (const float4*)emb_item, (const float4*)emb_author,
        (uint2*)embUb, (uint2*)embIb, (uint2*)embAb);
    k_arenainit<<<1, 1024, 0, stream>>>(binCur5,
        gg0.nbins, gg1.nbins, gg3.nbins, gg5.nbins, gg4.nbins,
        gg0.cap, gg1.cap, gg3.cap, gg5.cap, gg4.cap);

    auto build = [&](const int* row, const int* col, const float* val,
                     int E, int N, const G& g, int slot) {
        int* bc = binCur5 + slot * 1024;
        k_part1<<<nblk(E, 1024 * P1_ITER), 1024, 0, stream>>>(row, col, val, bc,
                                                              stage, E, g.shift,
                                                              g.nbins, g.cap);
        k_part2<<<g.nbins, 1024, 0, stream>>>(bc, stage, csr, rp2, N, g.shift, g.cap);
    };

    // ========== atom branch: 3-layer propagate on g0 ==========
    build(g0r, g0c, g0v, E0, NN0, gg0, 0);
    k_spmm<0, true><<<nblk(NN0, 4), B, 0, stream>>>(rp2, csr, embUb, embIb, NUu,
                                                    nullptr, nullptr, nullptr, nullptr,
                                                    nullptr, nullptr, nullptr,
                                                    y1b, nullptr, nullptr, NN0);
    k_spmm<0, false><<<nblk(NN0, 4), B, 0, stream>>>(rp2, csr, y1b, nullptr, 0,
                                                     nullptr, nullptr, nullptr, nullptr,
                                                     nullptr, nullptr, nullptr,
                                                     y2b, nullptr, nullptr, NN0);
    k_spmm<1, false><<<nblk(NN0, 4), B, 0, stream>>>(rp2, csr, y2b, nullptr, NUu,
                                                     emb_user, emb_item, y1b, y2b,
                                                     oUserA, items0, items0b,
                                                     nullptr, nullptr, nullptr, NN0);

    // ========== non-atom branch: 3-layer propagate on g1 ==========
    build(g1r, g1c, g1v, E1, NN1, gg1, 1);
    k_spmm<0, true><<<nblk(NN1, 4), B, 0, stream>>>(rp2, csr, embUb, embAb, NUu,
                                                    nullptr, nullptr, nullptr, nullptr,
                                                    nullptr, nullptr, nullptr,
                                                    y1b, nullptr, nullptr, NN1);
    k_spmm<0, false><<<nblk(NN1, 4), B, 0, stream>>>(rp2, csr, y1b, nullptr, 0,
                                                     nullptr, nullptr, nullptr, nullptr,
                                                     nullptr, nullptr, nullptr,
                                                     y2b, nullptr, nullptr, NN1);
    k_spmm<1, false><<<nblk(NN1, 4), B, 0, stream>>>(rp2, csr, y2b, nullptr, NUu,
                                                     emb_user, emb_author, y1b, y2b,
                                                     oUserN, oAuthN, oAuthNb,
                                                     nullptr, nullptr, nullptr, NN1);

    // ========== atom_authors = normalize(g3 @ items0) ==========
    build(g3r, g3c, g3v, E3, NAa, gg3, 2);
    k_spmm<2, false><<<nblk(NAa, 4), B, 0, stream>>>(rp2, csr, items0b, nullptr, 0,
                                                     nullptr, nullptr, nullptr, nullptr,
                                                     nullptr, nullptr, nullptr,
                                                     nullptr, oAuthA, nullptr, NAa);

    // ========== atom_items = 0.5*normalize(g5 @ items0) + 0.5*items0 ==========
    build(g5r, g5c, g5v, E5, NIi, gg5, 3);
    k_spmm<3, false><<<nblk(NIi, 4), B, 0, stream>>>(rp2, csr, items0b, nullptr, 0,
                                                     nullptr, nullptr, nullptr, nullptr,
                                                     nullptr, nullptr, nullptr,
                                                     nullptr, oItemA, items0, NIi);

    // ========== non_atom_items = normalize(g4 @ non_atom_authors) ==========
    build(g4r, g4c, g4v, E4, NIi, gg4, 4);
    k_spmm<2, false><<<nblk(NIi, 4), B, 0, stream>>>(rp2, csr, oAuthNb, nullptr, 0,
                                                     nullptr, nullptr, nullptr, nullptr,
                                                     nullptr, nullptr, nullptr,
                                                     nullptr, oItemN, nullptr, NIi);
}